// Round 1
// baseline (6255.645 us; speedup 1.0000x reference)
//
#include <hip/hip_runtime.h>

// LocallyConnected1d: out[b,o,l] = sum_{c,k} x[b,c,l+k] * w[o,c,l,k] + bias[o,l]
// B=32, Cin=Cout=128, L=2048, K=3, S=1, W=2050. All fp32.
//
// v2: latency-hiding rewrite.
//  - 1024 blocks x 512 threads -> 4 blocks/CU, 32 waves/CU (was 16).
//  - Weights staged through LDS (coalesced once, no 8x per-thread redundant
//    global loads); consumption is LDS broadcast.
//  - T14 split staging: global->reg loads for iter i+1 issued BEFORE compute
//    of iter i; regs->LDS after the WAR barrier. HBM latency hides under FMAs.
//  - Per-thread tile: 2(b) x 2(o) x 4(l) = 16 accumulators.

constexpr int CIN  = 128;
constexpr int COUT = 128;
constexpr int LL   = 2048;
constexpr int WID  = 2050;
constexpr int BATCH = 32;
constexpr int KK   = 3;

constexpr int O_TILE = 16;
constexpr int L_TILE = 16;
constexpr int CB = 4;             // channels per staged iteration
constexpr int TB = 2;             // batches per thread
constexpr int TO = 2;             // outputs per thread
constexpr int TL = 4;             // locations per thread
constexpr int XROW = 20;          // xs row stride (dwords); 18 used, 80 B rows
constexpr int WROW = 52;          // ws row stride (dwords); 48 used, 208 B rows
constexpr int NIT  = CIN / CB;    // 32
constexpr int W_ADV = CB * LL * KK;  // weight dword advance per iter
constexpr int X_ADV = CB * WID;      // x dword advance per iter

__global__ __launch_bounds__(512, 8)
void lc1d(const float* __restrict__ x, const float* __restrict__ w,
          const float* __restrict__ bias, float* __restrict__ out) {
  __shared__ float xs[CB * BATCH * XROW];   // 10240 B
  __shared__ float ws[CB * O_TILE * WROW];  // 13312 B  (23.5 KB total -> 4 blk/CU)

  const int tid = threadIdx.x;
  const int lg = tid & 3;          // l-group: 4 x TL=4
  const int og = (tid >> 2) & 7;   // o-group: 8 x TO=2
  const int bg = tid >> 5;         // b-group: 16 x TB=2
  const int bx = blockIdx.x;
  const int ltile = bx & 127;
  const int otile = bx >> 7;
  const int L0 = ltile * L_TILE;
  const int o_base = otile * O_TILE + og * TO;
  const int l_base = L0 + lg * TL;
  const int b0 = bg * TB;

  // ---- staging roles: waves 0-3 stage weights, waves 4-7 stage x ----
  const bool is_w = (tid < 256);
  int gofs, gc4 = 0, ldst, gadv;
  if (is_w) {
    const int seg  = tid >> 2;     // 0..63 == row (cs*16 + oo)
    const int part = tid & 3;      // 12 dwords each
    const int cs = seg >> 4, oo = seg & 15;
    gofs = ((otile * O_TILE + oo) * CIN + cs) * (LL * KK) + L0 * KK + part * 12;
    ldst = seg * WROW + part * 12;
    gadv = W_ADV;
  } else {
    const int u = tid - 256;
    const int row = u >> 1;        // 0..127 == (cs*32 + b)
    const int half = u & 1;        // 10 dwords each
    const int cs = row >> 5, b = row & 31;
    const int col0 = L0 + half * 10;
    gofs = (b * CIN + cs) * WID + col0;
    gc4 = min(col0 + 8, WID - 2) - col0;  // clamp last pair at tensor edge
    ldst = row * XROW + half * 10;
    gadv = X_ADV;
  }

  float pf[12];  // prefetch registers (w: 12 dwords, x: 10 dwords)

#define ISSUE() do {                                                          \
    if (is_w) {                                                               \
      const float4 a  = *reinterpret_cast<const float4*>(&w[gofs]);           \
      const float4 b4 = *reinterpret_cast<const float4*>(&w[gofs + 4]);       \
      const float4 c4 = *reinterpret_cast<const float4*>(&w[gofs + 8]);       \
      pf[0]=a.x;  pf[1]=a.y;  pf[2]=a.z;  pf[3]=a.w;                          \
      pf[4]=b4.x; pf[5]=b4.y; pf[6]=b4.z; pf[7]=b4.w;                         \
      pf[8]=c4.x; pf[9]=c4.y; pf[10]=c4.z; pf[11]=c4.w;                       \
    } else {                                                                  \
      const float2 p0 = *reinterpret_cast<const float2*>(&x[gofs]);           \
      const float2 p1 = *reinterpret_cast<const float2*>(&x[gofs + 2]);       \
      const float2 p2 = *reinterpret_cast<const float2*>(&x[gofs + 4]);       \
      const float2 p3 = *reinterpret_cast<const float2*>(&x[gofs + 6]);       \
      const float2 p4 = *reinterpret_cast<const float2*>(&x[gofs + gc4]);     \
      pf[0]=p0.x; pf[1]=p0.y; pf[2]=p1.x; pf[3]=p1.y;                         \
      pf[4]=p2.x; pf[5]=p2.y; pf[6]=p3.x; pf[7]=p3.y;                         \
      pf[8]=p4.x; pf[9]=p4.y;                                                 \
    }                                                                         \
    gofs += gadv;                                                             \
  } while (0)

#define WRITE() do {                                                          \
    if (is_w) {                                                               \
      *reinterpret_cast<float4*>(&ws[ldst])     =                             \
          make_float4(pf[0], pf[1], pf[2], pf[3]);                            \
      *reinterpret_cast<float4*>(&ws[ldst + 4]) =                             \
          make_float4(pf[4], pf[5], pf[6], pf[7]);                            \
      *reinterpret_cast<float4*>(&ws[ldst + 8]) =                             \
          make_float4(pf[8], pf[9], pf[10], pf[11]);                          \
    } else {                                                                  \
      *reinterpret_cast<float2*>(&xs[ldst])     = make_float2(pf[0], pf[1]);  \
      *reinterpret_cast<float2*>(&xs[ldst + 2]) = make_float2(pf[2], pf[3]);  \
      *reinterpret_cast<float2*>(&xs[ldst + 4]) = make_float2(pf[4], pf[5]);  \
      *reinterpret_cast<float2*>(&xs[ldst + 6]) = make_float2(pf[6], pf[7]);  \
      *reinterpret_cast<float2*>(&xs[ldst + 8]) = make_float2(pf[8], pf[9]);  \
    }                                                                         \
  } while (0)

  // ---- accumulators, initialized with bias (same bias for every batch) ----
  float acc[TB][TO][TL];
  #pragma unroll
  for (int oi = 0; oi < TO; ++oi) {
    const float4 bv =
        *reinterpret_cast<const float4*>(&bias[(o_base + oi) * LL + l_base]);
    #pragma unroll
    for (int bi = 0; bi < TB; ++bi) {
      acc[bi][oi][0] = bv.x; acc[bi][oi][1] = bv.y;
      acc[bi][oi][2] = bv.z; acc[bi][oi][3] = bv.w;
    }
  }

  // ---- prologue: stage iteration 0 ----
  ISSUE();
  WRITE();
  __syncthreads();

  #pragma unroll 1
  for (int it = 0; it < NIT; ++it) {
    const bool more = (it < NIT - 1);
    if (more) ISSUE();  // next iter's loads in flight across the whole compute

    #pragma unroll
    for (int cs = 0; cs < CB; ++cs) {
      const float* wr = &ws[(cs * O_TILE + og * TO) * WROW + lg * 12];
      const float* xr = &xs[(cs * BATCH + b0) * XROW + lg * TL];
      #pragma unroll
      for (int oi = 0; oi < TO; ++oi) {
        float4 wv[3];
        wv[0] = *reinterpret_cast<const float4*>(wr + oi * WROW);
        wv[1] = *reinterpret_cast<const float4*>(wr + oi * WROW + 4);
        wv[2] = *reinterpret_cast<const float4*>(wr + oi * WROW + 8);
        const float* wf = reinterpret_cast<const float*>(&wv[0]);
        #pragma unroll
        for (int bi = 0; bi < TB; ++bi) {
          const float4 xa = *reinterpret_cast<const float4*>(xr + bi * XROW);
          const float2 xb = *reinterpret_cast<const float2*>(xr + bi * XROW + 4);
          const float xv[6] = {xa.x, xa.y, xa.z, xa.w, xb.x, xb.y};
          #pragma unroll
          for (int j = 0; j < TL; ++j) {
            #pragma unroll
            for (int k = 0; k < KK; ++k)
              acc[bi][oi][j] = fmaf(wf[j * KK + k], xv[j + k], acc[bi][oi][j]);
          }
        }
      }
    }

    if (more) {
      __syncthreads();   // WAR: everyone done reading LDS
      WRITE();           // compiler waits vmcnt here; loads had ~full compute
      __syncthreads();   // RAW: tiles ready
    }
  }

  // ---- store: out[b, o, l_base..l_base+3] as float4 ----
  #pragma unroll
  for (int bi = 0; bi < TB; ++bi) {
    #pragma unroll
    for (int oi = 0; oi < TO; ++oi) {
      const float4 v = make_float4(acc[bi][oi][0], acc[bi][oi][1],
                                   acc[bi][oi][2], acc[bi][oi][3]);
      *reinterpret_cast<float4*>(
          &out[((b0 + bi) * COUT + o_base + oi) * LL + l_base]) = v;
    }
  }
#undef ISSUE
#undef WRITE
}

extern "C" void kernel_launch(void* const* d_in, const int* in_sizes, int n_in,
                              void* d_out, int out_size, void* d_ws, size_t ws_size,
                              hipStream_t stream) {
  const float* x    = (const float*)d_in[0];
  const float* wgt  = (const float*)d_in[1];
  const float* bias = (const float*)d_in[2];
  float* out = (float*)d_out;
  // 8 o-tiles x 128 l-tiles = 1024 blocks of 512 threads
  // -> 4 blocks/CU, 32 waves/CU (full occupancy), weight crosses HBM once.
  hipLaunchKernelGGL(lc1d, dim3(1024), dim3(512), 0, stream, x, wgt, bias, out);
}

// Round 2
// 5667.475 us; speedup vs baseline: 1.1038x; 1.1038x over previous
//
#include <hip/hip_runtime.h>

// LocallyConnected1d: out[b,o,l] = sum_{c,k} x[b,c,l+k] * w[o,c,l,k] + bias[o,l]
// B=32, Cin=Cout=128, L=2048, K=3, S=1, W=2050. All fp32.
//
// v3: v2 structure with the register-pressure fix.
//  - v2's __launch_bounds__(512,8) capped VGPRs at 64 -> compiler allocated 32
//    and spilled the inner loop to scratch (21 GB scratch traffic, 5.8 ms).
//  - (512,6) -> cap ~85 VGPRs, 3 blocks/CU, 24 waves/CU (75% occupancy).
//  - Everything else identical to v2: weights staged through LDS (coalesced
//    once), T14 split staging (global->reg issued before compute, reg->LDS
//    after the WAR barrier), per-thread tile 2(b) x 2(o) x 4(l).

constexpr int CIN  = 128;
constexpr int COUT = 128;
constexpr int LL   = 2048;
constexpr int WID  = 2050;
constexpr int BATCH = 32;
constexpr int KK   = 3;

constexpr int O_TILE = 16;
constexpr int L_TILE = 16;
constexpr int CB = 4;             // channels per staged iteration
constexpr int TB = 2;             // batches per thread
constexpr int TO = 2;             // outputs per thread
constexpr int TL = 4;             // locations per thread
constexpr int XROW = 20;          // xs row stride (dwords); 18 used, 80 B rows
constexpr int WROW = 52;          // ws row stride (dwords); 48 used, 208 B rows
constexpr int NIT  = CIN / CB;    // 32
constexpr int W_ADV = CB * LL * KK;  // weight dword advance per iter
constexpr int X_ADV = CB * WID;      // x dword advance per iter

__global__ __launch_bounds__(512, 6)
void lc1d(const float* __restrict__ x, const float* __restrict__ w,
          const float* __restrict__ bias, float* __restrict__ out) {
  __shared__ float xs[CB * BATCH * XROW];   // 10240 B
  __shared__ float ws[CB * O_TILE * WROW];  // 13312 B  (23.5 KB total)

  const int tid = threadIdx.x;
  const int lg = tid & 3;          // l-group: 4 x TL=4
  const int og = (tid >> 2) & 7;   // o-group: 8 x TO=2
  const int bg = tid >> 5;         // b-group: 16 x TB=2
  const int bx = blockIdx.x;
  const int ltile = bx & 127;
  const int otile = bx >> 7;
  const int L0 = ltile * L_TILE;
  const int o_base = otile * O_TILE + og * TO;
  const int l_base = L0 + lg * TL;
  const int b0 = bg * TB;

  // ---- staging roles: waves 0-3 stage weights, waves 4-7 stage x ----
  const bool is_w = (tid < 256);
  int gofs, gc4 = 0, ldst, gadv;
  if (is_w) {
    const int seg  = tid >> 2;     // 0..63 == row (cs*16 + oo)
    const int part = tid & 3;      // 12 dwords each
    const int cs = seg >> 4, oo = seg & 15;
    gofs = ((otile * O_TILE + oo) * CIN + cs) * (LL * KK) + L0 * KK + part * 12;
    ldst = seg * WROW + part * 12;
    gadv = W_ADV;
  } else {
    const int u = tid - 256;
    const int row = u >> 1;        // 0..127 == (cs*32 + b)
    const int half = u & 1;        // 10 dwords each
    const int cs = row >> 5, b = row & 31;
    const int col0 = L0 + half * 10;
    gofs = (b * CIN + cs) * WID + col0;
    gc4 = min(col0 + 8, WID - 2) - col0;  // clamp last pair at tensor edge
    ldst = row * XROW + half * 10;
    gadv = X_ADV;
  }

  float pf[12];  // prefetch registers (w: 12 dwords, x: 10 dwords)

#define ISSUE() do {                                                          \
    if (is_w) {                                                               \
      const float4 a  = *reinterpret_cast<const float4*>(&w[gofs]);           \
      const float4 b4 = *reinterpret_cast<const float4*>(&w[gofs + 4]);       \
      const float4 c4 = *reinterpret_cast<const float4*>(&w[gofs + 8]);       \
      pf[0]=a.x;  pf[1]=a.y;  pf[2]=a.z;  pf[3]=a.w;                          \
      pf[4]=b4.x; pf[5]=b4.y; pf[6]=b4.z; pf[7]=b4.w;                         \
      pf[8]=c4.x; pf[9]=c4.y; pf[10]=c4.z; pf[11]=c4.w;                       \
    } else {                                                                  \
      const float2 p0 = *reinterpret_cast<const float2*>(&x[gofs]);           \
      const float2 p1 = *reinterpret_cast<const float2*>(&x[gofs + 2]);       \
      const float2 p2 = *reinterpret_cast<const float2*>(&x[gofs + 4]);       \
      const float2 p3 = *reinterpret_cast<const float2*>(&x[gofs + 6]);       \
      const float2 p4 = *reinterpret_cast<const float2*>(&x[gofs + gc4]);     \
      pf[0]=p0.x; pf[1]=p0.y; pf[2]=p1.x; pf[3]=p1.y;                         \
      pf[4]=p2.x; pf[5]=p2.y; pf[6]=p3.x; pf[7]=p3.y;                         \
      pf[8]=p4.x; pf[9]=p4.y;                                                 \
    }                                                                         \
    gofs += gadv;                                                             \
  } while (0)

#define WRITE() do {                                                          \
    if (is_w) {                                                               \
      *reinterpret_cast<float4*>(&ws[ldst])     =                             \
          make_float4(pf[0], pf[1], pf[2], pf[3]);                            \
      *reinterpret_cast<float4*>(&ws[ldst + 4]) =                             \
          make_float4(pf[4], pf[5], pf[6], pf[7]);                            \
      *reinterpret_cast<float4*>(&ws[ldst + 8]) =                             \
          make_float4(pf[8], pf[9], pf[10], pf[11]);                          \
    } else {                                                                  \
      *reinterpret_cast<float2*>(&xs[ldst])     = make_float2(pf[0], pf[1]);  \
      *reinterpret_cast<float2*>(&xs[ldst + 2]) = make_float2(pf[2], pf[3]);  \
      *reinterpret_cast<float2*>(&xs[ldst + 4]) = make_float2(pf[4], pf[5]);  \
      *reinterpret_cast<float2*>(&xs[ldst + 6]) = make_float2(pf[6], pf[7]);  \
      *reinterpret_cast<float2*>(&xs[ldst + 8]) = make_float2(pf[8], pf[9]);  \
    }                                                                         \
  } while (0)

  // ---- accumulators, initialized with bias (same bias for every batch) ----
  float acc[TB][TO][TL];
  #pragma unroll
  for (int oi = 0; oi < TO; ++oi) {
    const float4 bv =
        *reinterpret_cast<const float4*>(&bias[(o_base + oi) * LL + l_base]);
    #pragma unroll
    for (int bi = 0; bi < TB; ++bi) {
      acc[bi][oi][0] = bv.x; acc[bi][oi][1] = bv.y;
      acc[bi][oi][2] = bv.z; acc[bi][oi][3] = bv.w;
    }
  }

  // ---- prologue: stage iteration 0 ----
  ISSUE();
  WRITE();
  __syncthreads();

  #pragma unroll 1
  for (int it = 0; it < NIT; ++it) {
    const bool more = (it < NIT - 1);
    if (more) ISSUE();  // next iter's loads in flight across the whole compute

    #pragma unroll
    for (int cs = 0; cs < CB; ++cs) {
      const float* wr = &ws[(cs * O_TILE + og * TO) * WROW + lg * 12];
      const float* xr = &xs[(cs * BATCH + b0) * XROW + lg * TL];
      #pragma unroll
      for (int oi = 0; oi < TO; ++oi) {
        float4 wv[3];
        wv[0] = *reinterpret_cast<const float4*>(wr + oi * WROW);
        wv[1] = *reinterpret_cast<const float4*>(wr + oi * WROW + 4);
        wv[2] = *reinterpret_cast<const float4*>(wr + oi * WROW + 8);
        const float* wf = reinterpret_cast<const float*>(&wv[0]);
        #pragma unroll
        for (int bi = 0; bi < TB; ++bi) {
          const float4 xa = *reinterpret_cast<const float4*>(xr + bi * XROW);
          const float2 xb = *reinterpret_cast<const float2*>(xr + bi * XROW + 4);
          const float xv[6] = {xa.x, xa.y, xa.z, xa.w, xb.x, xb.y};
          #pragma unroll
          for (int j = 0; j < TL; ++j) {
            #pragma unroll
            for (int k = 0; k < KK; ++k)
              acc[bi][oi][j] = fmaf(wf[j * KK + k], xv[j + k], acc[bi][oi][j]);
          }
        }
      }
    }

    if (more) {
      __syncthreads();   // WAR: everyone done reading LDS
      WRITE();           // compiler waits vmcnt here; loads had ~full compute
      __syncthreads();   // RAW: tiles ready
    }
  }

  // ---- store: out[b, o, l_base..l_base+3] as float4 ----
  #pragma unroll
  for (int bi = 0; bi < TB; ++bi) {
    #pragma unroll
    for (int oi = 0; oi < TO; ++oi) {
      const float4 v = make_float4(acc[bi][oi][0], acc[bi][oi][1],
                                   acc[bi][oi][2], acc[bi][oi][3]);
      *reinterpret_cast<float4*>(
          &out[((b0 + bi) * COUT + o_base + oi) * LL + l_base]) = v;
    }
  }
#undef ISSUE
#undef WRITE
}

extern "C" void kernel_launch(void* const* d_in, const int* in_sizes, int n_in,
                              void* d_out, int out_size, void* d_ws, size_t ws_size,
                              hipStream_t stream) {
  const float* x    = (const float*)d_in[0];
  const float* wgt  = (const float*)d_in[1];
  const float* bias = (const float*)d_in[2];
  float* out = (float*)d_out;
  // 8 o-tiles x 128 l-tiles = 1024 blocks of 512 threads
  // -> 3 blocks/CU resident (24 waves/CU), weight crosses HBM once.
  hipLaunchKernelGGL(lc1d, dim3(1024), dim3(512), 0, stream, x, wgt, bias, out);
}